// Round 15
// baseline (1213.102 us; speedup 1.0000x reference)
//
#include <hip/hip_runtime.h>

#define NB 512
#define NT 256
#define NI 32
#define NH 128
#define NG 512

typedef __attribute__((ext_vector_type(8))) short bf16x8;
typedef __attribute__((ext_vector_type(4))) float f32x4;

__device__ __forceinline__ float fsig(float x) { return 1.0f / (1.0f + __expf(-x)); }
__device__ __forceinline__ float ftanh(float x) {
    float ax = fabsf(x);
    float e  = __expf(-2.0f * ax);
    float t  = (1.0f - e) / (1.0f + e);
    return copysignf(t, x);
}
__device__ __forceinline__ unsigned short f2bf_rne(float f) {
    unsigned u = __float_as_uint(f);
    return (unsigned short)((u + 0x7FFFu + ((u >> 16) & 1u)) >> 16);
}
__device__ __forceinline__ void split2(float a, float b, unsigned& hi, unsigned& lo) {
    unsigned short ha = f2bf_rne(a), hb = f2bf_rne(b);
    float ra = a - __uint_as_float((unsigned)ha << 16);
    float rb = b - __uint_as_float((unsigned)hb << 16);
    hi = (unsigned)ha | ((unsigned)hb << 16);
    lo = (unsigned)f2bf_rne(ra) | ((unsigned)f2bf_rne(rb) << 16);
}
__device__ __forceinline__ bf16x8 u4bf(uint4 u) {
    union { uint4 u; bf16x8 v; } c; c.u = u; return c.v;
}
__device__ __forceinline__ unsigned packh(float h) {
    unsigned short hi = f2bf_rne(h);
    float r = h - __uint_as_float((unsigned)hi << 16);
    return (unsigned)hi | ((unsigned)f2bf_rne(r) << 16);
}
#define MFMA16(accv, av, bv) \
    accv = __builtin_amdgcn_mfma_f32_16x16x32_bf16(av, bv, accv, 0, 0, 0)

// LDS-only barrier: orders ds ops across waves WITHOUT draining vmcnt.
__device__ __forceinline__ void lds_barrier() {
    asm volatile("s_waitcnt lgkmcnt(0)\n\ts_barrier" ::: "memory");
}

// unpack two packed (hi|lo) uint4s into hi/lo bf16x8 A-frags
__device__ __forceinline__ void unpackHL(uint4 a, uint4 b, bf16x8& h, bf16x8& l) {
    uint4 H, L;
    H.x = (a.x & 0xffffu) | (a.y << 16);
    H.y = (a.z & 0xffffu) | (a.w << 16);
    H.z = (b.x & 0xffffu) | (b.y << 16);
    H.w = (b.z & 0xffffu) | (b.w << 16);
    L.x = (a.x >> 16) | (a.y & 0xffff0000u);
    L.y = (a.z >> 16) | (a.w & 0xffff0000u);
    L.z = (b.x >> 16) | (b.y & 0xffff0000u);
    L.w = (b.z >> 16) | (b.w & 0xffff0000u);
    h = u4bf(H); l = u4bf(L);
}

// ---------------------------------------------------------------------------
// Paired MFMA LSTM recurrence, R15: x-projection FUSED into role 0.
//   role 0 (blk  0-31): layer-0, chunk i. gates = [h|x] @ [w_hh0|w_ih0]^T + b
//     as 5 MFMA k-chunks: q=0..3 h (K=128), q=4 x (K=32). x staged per-step
//     into double-buffered WX (1 scalar load/thread, prefetched 1 step ahead);
//     w_ih0 hi-limbs in 16 extra VGPRs, lo-limbs in 4KB LDS; bias in 4 regs.
//     -> NO xg0 buffer, NO gemm<1> dispatches, ~no per-step global loads.
//   role 1 (blk 32-63): layer-1, chunk i-1 (reads xg1 from gemm<4>), as R14.
// Tc=64 now fits ws (xg0 gone) -> 10 dispatches total vs 33.
// LDS: Wl 128K + WA/WB 16K + Wlx 4K + WX 4K = 152K <= 160K.
// Regs role0 ~114 < 128 grant (R1-R6 ledger: keep >=10 margin).
// ---------------------------------------------------------------------------
__global__ __launch_bounds__(512, 1)
void recur_pair(const float* __restrict__ x,     // [NB][NT][NI]
                const float* __restrict__ xg1,   // [NB*Tc][NG] rows b*Tc+tl
                const float* __restrict__ w_ih0, // [NG][NI]
                const float* __restrict__ b_ih0, const float* __restrict__ b_hh0,
                const float* __restrict__ w_hh0,
                const float* __restrict__ w_hh1,
                float* __restrict__ h0buf,       // role0 hout [NB][Tc][NH]
                float* __restrict__ h0s, float* __restrict__ c0s,
                float* __restrict__ h1s, float* __restrict__ c1s,
                int Tc, int t0, int doA, int doB, int firstA, int firstB)
{
    __shared__ __align__(16) unsigned short Wl[128][64][8];   // 131072 B
    __shared__ __align__(16) unsigned WA[2][4][64][4];        // 8192 B
    __shared__ __align__(16) unsigned WB[2][4][64][4];        // 8192 B
    __shared__ __align__(16) unsigned short Wlx[4][64][8];    // 4096 B
    __shared__ __align__(16) unsigned WX[2][64][8];           // 4096 B

    const int role = blockIdx.x >> 5;
    if (role == 0 && !doA) return;
    if (role == 1 && !doB) return;

    const float* wsrc  = role ? w_hh1 : w_hh0;
    float*       hs    = role ? h1s : h0s;
    float*       cs    = role ? c1s : c0s;
    const int    first = role ? firstB : firstA;

    const int p    = blockIdx.x & 31;
    const int tid  = threadIdx.x;
    const int wv   = tid >> 6;
    const int lane = tid & 63;
    const int quad = lane >> 4;
    const int ml   = lane & 15;
    const int j    = 16 * wv + ml;

    // h-store coordinates (uniform in r): j -> (q_s, quad_s, dd, loA)
    const int q_s    = j >> 5;
    const int quad_s = (j >> 3) & 3;
    const int dd     = j & 3;
    const bool loA   = (j & 7) < 4;

    // x-staging coordinates (role 0)
    const int xm = tid & 15, xk = tid >> 4;          // m 0..15, k 0..31
    const int xL = (xk >> 3) * 16 + xm, xd = xk & 7;

    // ---- stage recurrent weights: hi -> regs, lo -> LDS (slot=lane) ----
    bf16x8 wh[4][4];
#pragma unroll
    for (int t = 0; t < 4; ++t) {
#pragma unroll
        for (int q = 0; q < 4; ++q) {
            int n = (t * 8 + wv) * 16 + ml;
            const float* s = wsrc + (size_t)n * NH + q * 32 + quad * 8;
            float4 v0 = *(const float4*)s;
            float4 v1 = *(const float4*)(s + 4);
            uint4 H, L;
            split2(v0.x, v0.y, H.x, L.x); split2(v0.z, v0.w, H.y, L.y);
            split2(v1.x, v1.y, H.z, L.z); split2(v1.z, v1.w, H.w, L.w);
            wh[t][q] = u4bf(H);
            *(uint4*)&Wl[(t * 8 + wv) * 4 + q][lane][0] = L;
        }
    }

    // ---- role-0 extras: w_ih0 (hi regs, lo LDS), bias, x[t0] staging ----
    bf16x8 whx[4];
    float bias4[4];
    if (role == 0) {
#pragma unroll
        for (int t = 0; t < 4; ++t) {
            int n = (t * 8 + wv) * 16 + ml;
            const float* s = w_ih0 + (size_t)n * NI + quad * 8;
            float4 v0 = *(const float4*)s;
            float4 v1 = *(const float4*)(s + 4);
            uint4 H, L;
            split2(v0.x, v0.y, H.x, L.x); split2(v0.z, v0.w, H.y, L.y);
            split2(v1.x, v1.y, H.z, L.z); split2(v1.z, v1.w, H.w, L.w);
            whx[t] = u4bf(H);
            *(uint4*)&Wlx[t][lane][0] = L;
            int g = t * 128 + j;
            bias4[t] = b_ih0[g] + b_hh0[g];
        }
        float xv = x[((size_t)(p * 16 + xm) * NT + t0) * NI + xk];
        WX[0][xL][xd] = packh(xv);
    }

    // ---- initial c/h ----
    float cr[4];
#pragma unroll
    for (int r = 0; r < 4; ++r) {
        int m = quad * 4 + r;
        float h = 0.f, c = 0.f;
        if (!first) {
            h = hs[(size_t)(p * 16 + m) * NH + j];
            c = cs[(size_t)(p * 16 + m) * NH + j];
        }
        cr[r] = c;
        unsigned pv = packh(h);
        if (loA) WA[0][q_s][quad_s * 16 + m][dd] = pv;
        else     WB[0][q_s][quad_s * 16 + m][dd] = pv;
    }
    __syncthreads();

    const size_t rs = (size_t)Tc * NG;
    const size_t rowb0 = ((size_t)(p * 16 + quad * 4) * Tc) * NG + j;

    for (int tl = 0; tl < Tc; ++tl) {
        const int buf = tl & 1, nbuf = buf ^ 1;

        // prefetches (issue early, consume late)
        float xnext = 0.f, xgv[4][4];
        if (role == 0) {
            int tn = t0 + tl + 1; if (tn > NT - 1) tn = NT - 1;
            xnext = x[((size_t)(p * 16 + xm) * NT + tn) * NI + xk];
        } else {
            const size_t rowb = rowb0 + (size_t)tl * NG;
#pragma unroll
            for (int t = 0; t < 4; ++t)
#pragma unroll
                for (int r = 0; r < 4; ++r)
                    xgv[t][r] = xg1[rowb + (size_t)r * rs + t * 128];
        }

        f32x4 acc[4] = {};
#pragma unroll
        for (int q = 0; q < 4; ++q) {
            uint4 wAv = *(const uint4*)&WA[buf][q][lane][0];   // dense b128
            uint4 wBv = *(const uint4*)&WB[buf][q][lane][0];
            bf16x8 ah, al;
            unpackHL(wAv, wBv, ah, al);
#pragma unroll
            for (int t = 0; t < 4; ++t) {
                bf16x8 wlv = *(const bf16x8*)&Wl[(t * 8 + wv) * 4 + q][lane][0];
                MFMA16(acc[t], ah, wh[t][q]);
                MFMA16(acc[t], al, wh[t][q]);
                MFMA16(acc[t], ah, wlv);
            }
        }
        if (role == 0) {   // 5th chunk: x @ w_ih0^T
            uint4 xA = *(const uint4*)&WX[buf][lane][0];
            uint4 xB = *(const uint4*)&WX[buf][lane][4];
            bf16x8 xh, xl;
            unpackHL(xA, xB, xh, xl);
#pragma unroll
            for (int t = 0; t < 4; ++t) {
                bf16x8 wlv = *(const bf16x8*)&Wlx[t][lane][0];
                MFMA16(acc[t], xh, whx[t]);
                MFMA16(acc[t], xl, whx[t]);
                MFMA16(acc[t], xh, wlv);
            }
        }

        // gate activation + c/h update
#pragma unroll
        for (int r = 0; r < 4; ++r) {
            float a0 = acc[0][r] + (role ? xgv[0][r] : bias4[0]);
            float a1 = acc[1][r] + (role ? xgv[1][r] : bias4[1]);
            float a2 = acc[2][r] + (role ? xgv[2][r] : bias4[2]);
            float a3 = acc[3][r] + (role ? xgv[3][r] : bias4[3]);
            float gi = fsig(a0), gf = fsig(a1), gg = ftanh(a2), go = fsig(a3);
            cr[r] = gf * cr[r] + gi * gg;
            float hn = go * ftanh(cr[r]);
            int m = quad * 4 + r;
            unsigned pv = packh(hn);
            if (loA) WA[nbuf][q_s][quad_s * 16 + m][dd] = pv;
            else     WB[nbuf][q_s][quad_s * 16 + m][dd] = pv;
            if (role == 0)
                h0buf[((size_t)(p * 16 + m) * Tc + tl) * NH + j] = hn;
            if (tl == Tc - 1) {
                hs[(size_t)(p * 16 + m) * NH + j] = hn;
                cs[(size_t)(p * 16 + m) * NH + j] = cr[r];
            }
        }
        if (role == 0)
            WX[nbuf][xL][xd] = packh(xnext);
        lds_barrier();   // LDS-only: don't drain global stores
    }
}

// ---------------------------------------------------------------------------
// Split-bf16 MFMA GEMM (R8-verified): C = A @ Bw^T + (bi+bh). K = KP*32.
// ---------------------------------------------------------------------------
template<int KP>
__global__ __launch_bounds__(256)
void gemm_mfma(const float* __restrict__ A,
               const float* __restrict__ Bw,
               const float* __restrict__ bi, const float* __restrict__ bh,
               float* __restrict__ C)
{
    constexpr int K = KP * 32;
    __shared__ __align__(16) unsigned short Ah[4][128][8], Al[4][128][8];
    __shared__ __align__(16) unsigned short Bh[4][64][8],  Bl[4][64][8];
    const int tid  = threadIdx.x;
    const int n0   = blockIdx.x * 64;
    const int m0   = blockIdx.y * 128;
    const int wv   = tid >> 6;
    const int lane = tid & 63;
    const int quad = lane >> 4, ml = lane & 15;

    f32x4 acc[2][4] = {};
    float bias[4];
#pragma unroll
    for (int nt = 0; nt < 4; ++nt) {
        int n = n0 + nt * 16 + ml;
        bias[nt] = bi[n] + bh[n];
    }

    for (int kp = 0; kp < KP; ++kp) {
        if (kp) __syncthreads();
#pragma unroll
        for (int r = 0; r < 2; ++r) {
            int u = tid + 256 * r;
            int m = u >> 2, ck = u & 3;
            const float* s = A + (size_t)(m0 + m) * K + kp * 32 + ck * 8;
            float4 v0 = *(const float4*)s;
            float4 v1 = *(const float4*)(s + 4);
            uint4 H, L;
            split2(v0.x, v0.y, H.x, L.x); split2(v0.z, v0.w, H.y, L.y);
            split2(v1.x, v1.y, H.z, L.z); split2(v1.z, v1.w, H.w, L.w);
            *(uint4*)&Ah[ck][m][0] = H;
            *(uint4*)&Al[ck][m][0] = L;
        }
        {
            int n = tid >> 2, ck = tid & 3;
            const float* s = Bw + (size_t)(n0 + n) * K + kp * 32 + ck * 8;
            float4 v0 = *(const float4*)s;
            float4 v1 = *(const float4*)(s + 4);
            uint4 H, L;
            split2(v0.x, v0.y, H.x, L.x); split2(v0.z, v0.w, H.y, L.y);
            split2(v1.x, v1.y, H.z, L.z); split2(v1.z, v1.w, H.w, L.w);
            *(uint4*)&Bh[ck][n][0] = H;
            *(uint4*)&Bl[ck][n][0] = L;
        }
        __syncthreads();

        bf16x8 ah0 = *(const bf16x8*)&Ah[quad][(2 * wv + 0) * 16 + ml][0];
        bf16x8 al0 = *(const bf16x8*)&Al[quad][(2 * wv + 0) * 16 + ml][0];
        bf16x8 ah1 = *(const bf16x8*)&Ah[quad][(2 * wv + 1) * 16 + ml][0];
        bf16x8 al1 = *(const bf16x8*)&Al[quad][(2 * wv + 1) * 16 + ml][0];
#pragma unroll
        for (int nt = 0; nt < 4; ++nt) {
            bf16x8 bhv = *(const bf16x8*)&Bh[quad][nt * 16 + ml][0];
            bf16x8 blv = *(const bf16x8*)&Bl[quad][nt * 16 + ml][0];
            MFMA16(acc[0][nt], ah0, bhv);
            MFMA16(acc[0][nt], ah0, blv);
            MFMA16(acc[0][nt], al0, bhv);
            MFMA16(acc[1][nt], ah1, bhv);
            MFMA16(acc[1][nt], ah1, blv);
            MFMA16(acc[1][nt], al1, bhv);
        }
    }

#pragma unroll
    for (int mt = 0; mt < 2; ++mt)
#pragma unroll
        for (int nt = 0; nt < 4; ++nt)
#pragma unroll
            for (int reg = 0; reg < 4; ++reg) {
                int m = m0 + (2 * wv + mt) * 16 + quad * 4 + reg;
                int n = n0 + nt * 16 + ml;
                C[(size_t)m * NG + n] = acc[mt][nt][reg] + bias[nt];
            }
}

// ---------------------------------------------------------------------------
// out[b] = fc2_w . relu(fc1_w @ h1_last[b] + fc1_b) + fc2_b
// ---------------------------------------------------------------------------
__global__ void fc_head(const float* __restrict__ h1,
                        const float* __restrict__ fc1w, const float* __restrict__ fc1b,
                        const float* __restrict__ fc2w, const float* __restrict__ fc2b,
                        float* __restrict__ out)
{
    int b = blockIdx.x, j = threadIdx.x;
    const float4* wr = (const float4*)(fc1w + (size_t)j * NH);
    const float4* hv = (const float4*)(h1 + (size_t)b * NH);
    float acc = fc1b[j];
#pragma unroll
    for (int q = 0; q < 32; ++q) {
        float4 w = wr[q], h = hv[q];
        acc += w.x * h.x + w.y * h.y + w.z * h.z + w.w * h.w;
    }
    float z = fmaxf(acc, 0.0f);
    float p = fc2w[j] * z;
#pragma unroll
    for (int off = 32; off > 0; off >>= 1) p += __shfl_down(p, off);
    if (j == 0) out[b] = p + fc2b[0];
}

extern "C" void kernel_launch(void* const* d_in, const int* in_sizes, int n_in,
                              void* d_out, int out_size, void* d_ws, size_t ws_size,
                              hipStream_t stream)
{
    const float* x     = (const float*)d_in[0];
    const float* w_ih0 = (const float*)d_in[1];
    const float* w_hh0 = (const float*)d_in[2];
    const float* b_ih0 = (const float*)d_in[3];
    const float* b_hh0 = (const float*)d_in[4];
    const float* w_ih1 = (const float*)d_in[5];
    const float* w_hh1 = (const float*)d_in[6];
    const float* b_ih1 = (const float*)d_in[7];
    const float* b_hh1 = (const float*)d_in[8];
    const float* fc1w  = (const float*)d_in[9];
    const float* fc1b  = (const float*)d_in[10];
    const float* fc2w  = (const float*)d_in[11];
    const float* fc2b  = (const float*)d_in[12];
    float* out = (float*)d_out;
    float* ws  = (float*)d_ws;

    // xg1 + h0 + 4 state arrays (xg0 eliminated -> Tc=64 fits the R8 budget)
    int Tc = 1;
    for (int cand = 256; cand >= 1; cand >>= 1) {
        size_t need = 4ull * ((size_t)NB * cand * (NG + NH) + 4ull * NB * NH);
        if (need <= ws_size) { Tc = cand; break; }
    }

    size_t o_xg1 = 0;
    size_t o_h0  = o_xg1 + (size_t)NB * Tc * NG;
    size_t o_h0s = o_h0  + (size_t)NB * Tc * NH;
    size_t o_c0s = o_h0s + (size_t)NB * NH;
    size_t o_h1s = o_c0s + (size_t)NB * NH;
    size_t o_c1s = o_h1s + (size_t)NB * NH;

    const int M = NB * Tc;
    const int nchunk = NT / Tc;

    for (int i = 0; i <= nchunk; ++i) {
        int doA = (i < nchunk), doB = (i >= 1);
        recur_pair<<<64, 512, 0, stream>>>(
            x, ws + o_xg1, w_ih0, b_ih0, b_hh0, w_hh0, w_hh1, ws + o_h0,
            ws + o_h0s, ws + o_c0s, ws + o_h1s, ws + o_c1s,
            Tc, i * Tc, doA, doB, i == 0, i == 1);
        if (i < nchunk)   // xg1 for chunk i (consumed by role1 next dispatch)
            gemm_mfma<4><<<dim3(8, M / 128), 256, 0, stream>>>(
                ws + o_h0, w_ih1, b_ih1, b_hh1, ws + o_xg1);
    }
    fc_head<<<NB, 64, 0, stream>>>(ws + o_h1s, fc1w, fc1b, fc2w, fc2b, out);
}